// Round 7
// baseline (183.638 us; speedup 1.0000x reference)
//
#include <hip/hip_runtime.h>

#define N_NODES 5000
#define N_EDGES 160000
#define HID 64
#define BATCH 512
#define NPB 20            // nodes per build block (250 blocks)
#define BSTRIDE 128       // bucket stride: mean deg 32, sigma 5.7 -> 17 sigma margin

// ws layout (bytes):
//   0        deg        5000 i32
//   20000    sorted_src 5000*128 i32   (2.56 MB)
//   2580000  h1         5000*64 f32    (1.28 MB)
//   3860000  h_part     5000*64 f32    (1.28 MB)
//   5140000  t_part     512*64 f32     (128 KB)

// ---------- dispatch 1: node-parallel bucket build + SAGE layer 1 + task MLP ----------
// blocks 0..249   : own 20 nodes each; scan all dsts, bucket own edges in LDS,
//                   then layer1 (mean @ Wl1.T + x @ Wr1.T) straight from LDS.
// blocks 250..313 : task MLP + t-half of classifier (8 batch rows per block).
__global__ __launch_bounds__(512) void build_kernel(
        const float* __restrict__ x, const int* __restrict__ ei,
        const float* __restrict__ Wl1, const float* __restrict__ bl1,
        const float* __restrict__ Wr1,
        const float* __restrict__ task_feat,
        const float* __restrict__ Wt1, const float* __restrict__ bt1,
        const float* __restrict__ Wt2, const float* __restrict__ bt2,
        const float* __restrict__ Wc1, const float* __restrict__ bc1,
        int* __restrict__ deg, int* __restrict__ sorted_src,
        float* __restrict__ h1, float* __restrict__ t_part) {
    int tid = threadIdx.x;
    int blk = blockIdx.x;
    __shared__ union SM {
        struct { int ldeg[NPB]; int lbuck[NPB][BSTRIDE]; } a;   // 10.3 KB
        struct { float s1[8][64]; float s2[8][64]; } t;         // 4 KB
    } sm;

    if (blk < N_NODES / NPB) {
        int n0 = blk * NPB;
        if (tid < NPB) sm.a.ldeg[tid] = 0;
        __syncthreads();

        // scan all edge dsts (int4 loads, coalesced); keep edges whose dst is ours
        const int4* dst4 = (const int4*)(ei + N_EDGES);
        for (int j4 = tid; j4 < N_EDGES / 4; j4 += 512) {
            int4 d = dst4[j4];
            int e = j4 * 4;
            unsigned r;
            r = (unsigned)(d.x - n0);
            if (r < NPB) { int q = atomicAdd(&sm.a.ldeg[r], 1); if (q < BSTRIDE) sm.a.lbuck[r][q] = ei[e]; }
            r = (unsigned)(d.y - n0);
            if (r < NPB) { int q = atomicAdd(&sm.a.ldeg[r], 1); if (q < BSTRIDE) sm.a.lbuck[r][q] = ei[e + 1]; }
            r = (unsigned)(d.z - n0);
            if (r < NPB) { int q = atomicAdd(&sm.a.ldeg[r], 1); if (q < BSTRIDE) sm.a.lbuck[r][q] = ei[e + 2]; }
            r = (unsigned)(d.w - n0);
            if (r < NPB) { int q = atomicAdd(&sm.a.ldeg[r], 1); if (q < BSTRIDE) sm.a.lbuck[r][q] = ei[e + 3]; }
        }
        __syncthreads();

        // layer 1 from LDS buckets: 8 groups of 64 lanes, nodes round-robin
        int lane = tid & 63, grp = tid >> 6;
        int f = lane & 3, g = lane >> 2;
        for (int ln = grp; ln < NPB; ln += 8) {
            int n = n0 + ln;
            int d = sm.a.ldeg[ln];
            if (d > BSTRIDE) d = BSTRIDE;
            float acc = 0.f;
            for (int j = g; j < d; j += 16) acc += x[sm.a.lbuck[ln][j] * 4 + f];
            acc += __shfl_down(acc, 32);
            acc += __shfl_down(acc, 16);
            acc += __shfl_down(acc, 8);
            acc += __shfl_down(acc, 4);
            float inv = 1.f / fmaxf((float)d, 1.f);
            float m0 = __shfl(acc, 0) * inv;
            float m1 = __shfl(acc, 1) * inv;
            float m2 = __shfl(acc, 2) * inv;
            float m3 = __shfl(acc, 3) * inv;
            float4 xv = ((const float4*)x)[n];
            float4 wl = ((const float4*)Wl1)[lane];    // row `lane` of Wl1 (64x4)
            float4 wr = ((const float4*)Wr1)[lane];
            float v = bl1[lane]
                    + m0 * wl.x + m1 * wl.y + m2 * wl.z + m3 * wl.w
                    + xv.x * wr.x + xv.y * wr.y + xv.z * wr.z + xv.w * wr.w;
            h1[n * 64 + lane] = fmaxf(v, 0.f);
            if (lane == 0) deg[n] = d;
            for (int j = lane; j < d; j += 64)
                sorted_src[n * BSTRIDE + j] = sm.a.lbuck[ln][j];
        }
    } else {
        // task MLP: t = (relu(tf@Wt1.T+bt1))@Wt2.T+bt2 ; t_part = t@Wc1[:,64:].T+bc1
        int lane = tid & 63, grp = tid >> 6;
        int b = (blk - N_NODES / NPB) * 8 + grp;
        float4 tf = ((const float4*)task_feat)[b];
        float4 w1 = ((const float4*)Wt1)[lane];
        float v = bt1[lane] + tf.x * w1.x + tf.y * w1.y + tf.z * w1.z + tf.w * w1.w;
        sm.t.s1[grp][lane] = fmaxf(v, 0.f);
        __syncthreads();
        const float4* w2r = (const float4*)(Wt2 + lane * 64);   // row `lane` of Wt2
        const float4* s1v = (const float4*)sm.t.s1[grp];
        float v2 = bt2[lane];
#pragma unroll
        for (int q = 0; q < 16; q++) {
            float4 w = w2r[q]; float4 s = s1v[q];
            v2 += s.x * w.x + s.y * w.y + s.z * w.z + s.w * w.w;
        }
        sm.t.s2[grp][lane] = v2;          // no relu on 2nd task layer
        __syncthreads();
        const float4* wcr = (const float4*)(Wc1 + lane * 128 + 64);  // t-half of row
        const float4* s2v = (const float4*)sm.t.s2[grp];
        float p = bc1[lane];
#pragma unroll
        for (int q = 0; q < 16; q++) {
            float4 w = wcr[q]; float4 s = s2v[q];
            p += s.x * w.x + s.y * w.y + s.z * w.z + s.w * w.w;
        }
        t_part[b * 64 + lane] = p;
    }
}

// ---------- dispatch 2: SAGE layer 2 (64->64) fused with h_part = h2 @ Wc1[:,:64].T ----
__global__ __launch_bounds__(256) void layer2_kernel(
        const float* __restrict__ h1, const int* __restrict__ deg,
        const int* __restrict__ sorted_src,
        const float* __restrict__ Wl2, const float* __restrict__ bl2,
        const float* __restrict__ Wr2, const float* __restrict__ Wc1,
        float* __restrict__ h_part) {
    int h = threadIdx.x & 63, grp = threadIdx.x >> 6;
    int n = blockIdx.x * 4 + grp;
    int d = deg[n];
    const int* bucket = sorted_src + n * BSTRIDE;
    float a0 = 0.f, a1 = 0.f, a2 = 0.f, a3 = 0.f;
    int j = 0;
    for (; j + 4 <= d; j += 4) {
        int e0 = bucket[j], e1 = bucket[j + 1], e2 = bucket[j + 2], e3 = bucket[j + 3];
        a0 += h1[e0 * 64 + h];
        a1 += h1[e1 * 64 + h];
        a2 += h1[e2 * 64 + h];
        a3 += h1[e3 * 64 + h];
    }
    for (; j < d; j++) a0 += h1[bucket[j] * 64 + h];
    float m = (a0 + a1 + a2 + a3) / fmaxf((float)d, 1.f);

    __shared__ float shm[4][64], shh[4][64], shh2[4][64];
    shm[grp][h] = m;
    shh[grp][h] = h1[n * 64 + h];
    __syncthreads();
    const float4* wl2r = (const float4*)(Wl2 + h * 64);   // row h (row-major, no transpose)
    const float4* wr2r = (const float4*)(Wr2 + h * 64);
    const float* im = shm[grp];
    const float* ih = shh[grp];
    float v = bl2[h];
#pragma unroll
    for (int q = 0; q < 16; q++) {
        float4 a = wl2r[q]; float4 b = wr2r[q];
        v += im[4 * q + 0] * a.x + im[4 * q + 1] * a.y + im[4 * q + 2] * a.z + im[4 * q + 3] * a.w
           + ih[4 * q + 0] * b.x + ih[4 * q + 1] * b.y + ih[4 * q + 2] * b.z + ih[4 * q + 3] * b.w;
    }
    shh2[grp][h] = fmaxf(v, 0.f);
    __syncthreads();
    const float4* wcr = (const float4*)(Wc1 + h * 128);   // h-half of row h
    const float* i2 = shh2[grp];
    float p = 0.f;
#pragma unroll
    for (int q = 0; q < 16; q++) {
        float4 c = wcr[q];
        p += i2[4 * q + 0] * c.x + i2[4 * q + 1] * c.y + i2[4 * q + 2] * c.z + i2[4 * q + 3] * c.w;
    }
    h_part[n * 64 + h] = p;
}

// ---------- dispatch 3: scores[b,n] = sum_h relu(hp[n,h]+tp[b,h])*Wc2[h] + bc2 ----------
__global__ __launch_bounds__(256) void scores_kernel(
        const float* __restrict__ h_part, const float* __restrict__ t_part,
        const float* __restrict__ Wc2, const float* __restrict__ bc2,
        float* __restrict__ out) {
    int tid = threadIdx.x;
    int n = blockIdx.x * 256 + tid;
    bool valid = n < N_NODES;
    int nn = valid ? n : (N_NODES - 1);
    float hr[64];
    const float4* hp = (const float4*)(h_part + nn * 64);
#pragma unroll
    for (int i = 0; i < 16; i++) {
        float4 v = hp[i];
        hr[4 * i + 0] = v.x; hr[4 * i + 1] = v.y;
        hr[4 * i + 2] = v.z; hr[4 * i + 3] = v.w;
    }
    float b2 = bc2[0];
    int b0 = blockIdx.y * 8;                       // 64 b-tiles of 8
    for (int bb = 0; bb < 8; bb++) {
        const float* tp = t_part + (b0 + bb) * 64; // block-uniform -> scalar loads
        float acc = 0.f;
#pragma unroll
        for (int h = 0; h < 64; h++)
            acc = fmaf(fmaxf(hr[h] + tp[h], 0.f), Wc2[h], acc);
        if (valid) out[(b0 + bb) * N_NODES + n] = acc + b2;
    }
}

// ---------- launch ----------
extern "C" void kernel_launch(void* const* d_in, const int* in_sizes, int n_in,
                              void* d_out, int out_size, void* d_ws, size_t ws_size,
                              hipStream_t stream) {
    const float* x    = (const float*)d_in[0];
    const int*   ei   = (const int*)d_in[1];
    const float* task = (const float*)d_in[2];
    const float* Wl1  = (const float*)d_in[3];
    const float* bl1  = (const float*)d_in[4];
    const float* Wr1  = (const float*)d_in[5];
    const float* Wl2  = (const float*)d_in[6];
    const float* bl2  = (const float*)d_in[7];
    const float* Wr2  = (const float*)d_in[8];
    const float* Wt1  = (const float*)d_in[9];
    const float* bt1  = (const float*)d_in[10];
    const float* Wt2  = (const float*)d_in[11];
    const float* bt2  = (const float*)d_in[12];
    const float* Wc1  = (const float*)d_in[13];
    const float* bc1  = (const float*)d_in[14];
    const float* Wc2  = (const float*)d_in[15];
    const float* bc2  = (const float*)d_in[16];
    float* out = (float*)d_out;

    char* ws = (char*)d_ws;
    int*   deg        = (int*)(ws + 0);
    int*   sorted_src = (int*)(ws + 20000);
    float* h1         = (float*)(ws + 2580000);
    float* h_part     = (float*)(ws + 3860000);
    float* t_part     = (float*)(ws + 5140000);

    build_kernel<<<N_NODES / NPB + BATCH / 8, 512, 0, stream>>>(
        x, ei, Wl1, bl1, Wr1, task, Wt1, bt1, Wt2, bt2, Wc1, bc1,
        deg, sorted_src, h1, t_part);
    layer2_kernel<<<N_NODES / 4, 256, 0, stream>>>(h1, deg, sorted_src,
                                                   Wl2, bl2, Wr2, Wc1, h_part);
    scores_kernel<<<dim3(20, 64), 256, 0, stream>>>(h_part, t_part, Wc2, bc2, out);
}